// Round 6
// baseline (53.424 us; speedup 1.0000x reference)
//
#include <hip/hip_runtime.h>
#include <hip/hip_bf16.h>
#include <cstdint>

// LearnableUpsamplingLayer: polyphase decomposition + bf16 MFMA.
// B=8, T=16384, C=64, F=64, filter=5, leaky 0.3.
// out[b,2t+p,f] = sum_tap M_p[tap][c,f] * x[t-1+tap, c]   (x outside [0,T) = 0)
// Even p=0: 3 taps; odd p=1: 4 taps. Frames 0,1 get a precomputed correction
// (the polyphase substitution leaks a (1-w)*x[0] term through blend[-1]).
//
// R6: barrier-free waves, operand-swapped MFMA (W=A so each thread owns 4
// consecutive filters -> dwordx4 stores). NEW: per-wave 32-row LDS ring
// buffer (each window stages only its 16 new frames, exactly 4 dwordx4 per
// lane), register prefetch depth 2 (loads for window w+2 in flight while
// computing w -> ~2 iterations of latency hiding), 8 windows per wave,
// grid 1024 = 4 blocks/CU exactly.

#define T_ 16384
#define TWO_T 32768
#define XSTRIDE 72         // ushorts per frame row (144B; benign alias, 16B aligned)
#define RING 32            // rows per wave ring buffer

typedef __bf16 bf16x8 __attribute__((ext_vector_type(8)));
typedef __bf16 bf16x4 __attribute__((ext_vector_type(4)));
typedef float  f32x4  __attribute__((ext_vector_type(4)));
typedef unsigned short u16x8 __attribute__((ext_vector_type(8)));

__device__ __forceinline__ float sigmoidf_(float z) {
    return 1.0f / (1.0f + expf(-z));
}

__device__ __forceinline__ unsigned short f2bf(float f) {
    union { float f; uint32_t u; } v; v.f = f;
    uint32_t u = v.u;
    return (unsigned short)((u + 0x7FFFu + ((u >> 16) & 1u)) >> 16);
}

// ---------------- prep: 64 blocks x 64 threads (layout unchanged).
// Blocks 0..55: the 7 polyphase matrices as packed bf16 fragments:
//   frag (phase, ks, nt): lane l elem i = M[tap=ks>>1][c=(ks&1)*32+(l>>4)*8+i]
//                                          [f=nt*16+(l&15)]
// Blocks 56..63: b = fi-56; corr[b][{E,O}][f] = sum_c K[{1,0}][c][f]*(1-w_c)*x[b,0,c]
__global__ void lu_prep_kernel(const float* __restrict__ iw,
                               const float* __restrict__ ck,
                               const float* __restrict__ x,
                               unsigned short* __restrict__ bp,
                               float* __restrict__ corrf) {
    int fi = blockIdx.x;
    int l  = threadIdx.x;
    if (fi < 56) {
        int phase, ks, nt;
        if (fi < 24) { phase = 0; ks = fi >> 2; nt = fi & 3; }
        else         { phase = 1; ks = (fi - 24) >> 2; nt = (fi - 24) & 3; }
        int tap = ks >> 1;
        int n   = nt * 16 + (l & 15);
        int c0  = ((ks & 1) << 5) + ((l >> 4) << 3);
        u16x8 pk;
#pragma unroll
        for (int i = 0; i < 8; ++i) {
            int c = c0 + i;
            float w = sigmoidf_(iw[c]);
            float v;
            #define CK(k) ck[((k) * 64 + c) * 64 + n]
            if (phase == 0) {
                if (tap == 0)      v = CK(0) + w * CK(1);
                else if (tap == 1) v = (1.f - w) * CK(1) + CK(2) + w * CK(3);
                else               v = (1.f - w) * CK(3) + CK(4);
            } else {
                if (tap == 0)      v = w * CK(0);
                else if (tap == 1) v = (1.f - w) * CK(0) + CK(1) + w * CK(2);
                else if (tap == 2) v = (1.f - w) * CK(2) + CK(3) + w * CK(4);
                else               v = (1.f - w) * CK(4);
            }
            #undef CK
            pk[i] = f2bf(v);
        }
        *(u16x8*)(bp + (((size_t)fi * 64) + l) * 8) = pk;
    } else {
        int b = fi - 56;
        int f = l;
        float cE = 0.f, cO = 0.f;
#pragma unroll
        for (int c = 0; c < 64; ++c) {
            float w = sigmoidf_(iw[c]);
            float g = (1.f - w) * x[(size_t)b * T_ * 64 + c];
            cE += ck[(64 + c) * 64 + f] * g;   // K1
            cO += ck[c * 64 + f] * g;          // K0
        }
        corrf[b * 128 + f]      = cE;
        corrf[b * 128 + 64 + f] = cO;
    }
}

// ---------------- main ----------------
// Load 16 frames [f0 .. f0+15], 4 dwordx4 per lane (no predication waste).
__device__ __forceinline__ void issue16(const float* __restrict__ xb,
                                        int f0, int lane, float4* ld) {
#pragma unroll
    for (int i = 0; i < 4; ++i) {
        int idx = i * 64 + lane;
        int j   = idx >> 4;
        int c4  = (idx & 15) << 2;
        int gf  = f0 + j;
        float4 v = make_float4(0.f, 0.f, 0.f, 0.f);
        if (gf < T_)                        // gf >= 2 always
            v = *(const float4*)(xb + (size_t)gf * 64 + c4);
        ld[i] = v;
    }
}

__global__ __launch_bounds__(256, 4) void lu_main_kernel(
        const float* __restrict__ x,
        const unsigned short* __restrict__ bp,
        const float* __restrict__ corrf,
        const float* __restrict__ bias,
        float* __restrict__ out) {
    __shared__ __align__(16) unsigned short xl[4][RING * XSTRIDE]; // 18,432 B

    const int bid  = blockIdx.x;        // 0..1023
    const int b    = bid >> 7;
    const int q    = bid & 127;
    const int p0   = q << 7;            // 128 time-pairs per block
    const int lane = threadIdx.x & 63;
    const int wv   = threadIdx.x >> 6;  // wave = filter tile

    unsigned short* xw = &xl[wv][0];
    const float* xb = x + (size_t)b * T_ * 64;

    // ---- prologue loads: frames p0-1..p0+1 (ring rows 31,0,1) ----
    float4 pro = make_float4(0.f, 0.f, 0.f, 0.f);
    {
        int j = lane >> 4, c4 = (lane & 15) << 2;
        int gf = p0 - 1 + j;
        if (lane < 48 && gf >= 0)
            pro = *(const float4*)(xb + (size_t)gf * 64 + c4);
    }
    // ---- depth-2 window prefetch ----
    float4 ldb[2][4];
    issue16(xb, p0 + 2,  lane, ldb[0]);   // window 0's new frames
    issue16(xb, p0 + 18, lane, ldb[1]);   // window 1's new frames

    // ---- weight A-fragments for this wave's filter tile (loaded once) ----
    bf16x8 We[6], Wo[8];
#pragma unroll
    for (int ks = 0; ks < 6; ++ks)
        We[ks] = __builtin_bit_cast(bf16x8,
            *(const u16x8*)(bp + (((size_t)(ks * 4 + wv)) * 64 + lane) * 8));
#pragma unroll
    for (int ks = 0; ks < 8; ++ks)
        Wo[ks] = __builtin_bit_cast(bf16x8,
            *(const u16x8*)(bp + (((size_t)(24 + ks * 4 + wv)) * 64 + lane) * 8));

    const int hi  = lane >> 4;
    const int col = lane & 15;          // time-pair within window
    const float4 bias4 = *(const float4*)(bias + (wv << 4) + (hi << 2));

    // ---- prologue ds_write (rows 31,0,1) ----
    if (lane < 48) {
        int j = lane >> 4, c4 = (lane & 15) << 2;
        int r = (j + 31) & 31;
        bf16x4 pk;
        pk[0] = (__bf16)pro.x; pk[1] = (__bf16)pro.y;
        pk[2] = (__bf16)pro.z; pk[3] = (__bf16)pro.w;
        *(bf16x4*)(xw + r * XSTRIDE + c4) = pk;
    }

#pragma unroll
    for (int w = 0; w < 8; ++w) {
        const int par = w & 1;

        // ---- cvt + ds_write window w's 16 new frames (ring rows) ----
#pragma unroll
        for (int i = 0; i < 4; ++i) {
            int idx = i * 64 + lane;
            int j   = idx >> 4;
            int c4  = (idx & 15) << 2;
            int r   = (16 * w + 2 + j) & 31;
            bf16x4 pk;
            pk[0] = (__bf16)ldb[par][i].x; pk[1] = (__bf16)ldb[par][i].y;
            pk[2] = (__bf16)ldb[par][i].z; pk[3] = (__bf16)ldb[par][i].w;
            *(bf16x4*)(xw + r * XSTRIDE + c4) = pk;
        }

        // ---- refill this buffer with window w+2 (stays in flight) ----
        if (w < 6) issue16(xb, p0 + 16 * (w + 2) + 2, lane, ldb[par]);

        // ---- B reads (x, ring-indexed) + 14 MFMA ----
        f32x4 accE = {0.f, 0.f, 0.f, 0.f};
        f32x4 accO = {0.f, 0.f, 0.f, 0.f};
#pragma unroll
        for (int tap = 0; tap < 4; ++tap) {
            const int r = (16 * w - 1 + col + tap) & 31;
#pragma unroll
            for (int h = 0; h < 2; ++h) {
                bf16x8 xfr = __builtin_bit_cast(bf16x8,
                    *(const u16x8*)(xw + r * XSTRIDE + (h << 5) + (hi << 3)));
                int ks = tap * 2 + h;
                if (tap < 3)
                    accE = __builtin_amdgcn_mfma_f32_16x16x32_bf16(We[ks], xfr, accE, 0, 0, 0);
                accO = __builtin_amdgcn_mfma_f32_16x16x32_bf16(Wo[ks], xfr, accO, 0, 0, 0);
            }
        }

        // ---- boundary correction (output frames 0,1 of each batch) ----
        if (((q | w) == 0) && col == 0) {
            const float4 cE4 = *(const float4*)(corrf + b * 128 + (wv << 4) + (hi << 2));
            const float4 cO4 = *(const float4*)(corrf + b * 128 + 64 + (wv << 4) + (hi << 2));
            accE[0] -= cE4.x; accE[1] -= cE4.y; accE[2] -= cE4.z; accE[3] -= cE4.w;
            accO[0] -= cO4.x; accO[1] -= cO4.y; accO[2] -= cO4.z; accO[3] -= cO4.w;
        }

        // ---- epilogue: bias + leaky_relu, one dwordx4 store per phase ----
        const int tl = p0 + (w << 4) + col;
        const size_t fbase = ((size_t)b * TWO_T + ((size_t)tl << 1)) * 64
                           + (wv << 4) + (hi << 2);
        float4 vE, vO;
        {
            float e0 = accE[0] + bias4.x, e1 = accE[1] + bias4.y,
                  e2 = accE[2] + bias4.z, e3 = accE[3] + bias4.w;
            vE.x = e0 >= 0.f ? e0 : 0.3f * e0;
            vE.y = e1 >= 0.f ? e1 : 0.3f * e1;
            vE.z = e2 >= 0.f ? e2 : 0.3f * e2;
            vE.w = e3 >= 0.f ? e3 : 0.3f * e3;
            float o0 = accO[0] + bias4.x, o1 = accO[1] + bias4.y,
                  o2 = accO[2] + bias4.z, o3 = accO[3] + bias4.w;
            vO.x = o0 >= 0.f ? o0 : 0.3f * o0;
            vO.y = o1 >= 0.f ? o1 : 0.3f * o1;
            vO.z = o2 >= 0.f ? o2 : 0.3f * o2;
            vO.w = o3 >= 0.f ? o3 : 0.3f * o3;
        }
        *(float4*)(out + fbase)      = vE;   // even frame 2*tl
        *(float4*)(out + fbase + 64) = vO;   // odd frame 2*tl+1
    }
}

extern "C" void kernel_launch(void* const* d_in, const int* in_sizes, int n_in,
                              void* d_out, int out_size, void* d_ws, size_t ws_size,
                              hipStream_t stream) {
    (void)in_sizes; (void)n_in; (void)out_size; (void)ws_size;
    const float* x    = (const float*)d_in[0];
    const float* iw   = (const float*)d_in[1];
    const float* ck   = (const float*)d_in[2];
    const float* bias = (const float*)d_in[3];
    float* out = (float*)d_out;
    unsigned short* bp = (unsigned short*)d_ws;            // 57,344 B
    float* corrf = (float*)((char*)d_ws + 57344);          // 4,096 B

    lu_prep_kernel<<<64, 64, 0, stream>>>(iw, ck, x, bp, corrf);
    lu_main_kernel<<<1024, 256, 0, stream>>>(x, bp, corrf, bias, out);
}

// Round 8
// 33.216 us; speedup vs baseline: 1.6084x; 1.6084x over previous
//
#include <hip/hip_runtime.h>
#include <hip/hip_bf16.h>
#include <cstdint>

// LearnableUpsamplingLayer: polyphase decomposition + bf16 MFMA.
// B=8, T=16384, C=64, F=64, filter=5, leaky 0.3.
// out[b,2t+p,f] = sum_tap M_p[tap][c,f] * x[t-1+tap, c]   (x outside [0,T) = 0)
// Even p=0: 3 taps; odd p=1: 4 taps. Frames 0,1 get a precomputed correction
// (the polyphase substitution leaks a (1-w)*x[0] term through blend[-1]).
//
// R8 = R7 + the missing vmcnt discipline. global_load_lds completes via
// vmcnt; with no __syncthreads the compiler emits NO wait between the DMA
// and the ds_reads (R7's garbage). Explicit counted s_waitcnt vmcnt(N)
// (never 0 in steady state) + sched_barrier(0) before each window's
// fragment reads: w0 -> vmcnt(4), w1/w2 -> vmcnt(6), w3 -> vmcnt(2).
// Weight/bias loads issued BEFORE the prologue DMAs so they are strictly
// older than every wait point.

#define T_ 16384
#define TWO_T 32768
#define RING 40            // f32 frames per wave ring (40*256B = 10 KB)

typedef __bf16 bf16x8 __attribute__((ext_vector_type(8)));
typedef float  f32x4  __attribute__((ext_vector_type(4)));
typedef unsigned short u16x8 __attribute__((ext_vector_type(8)));

__device__ __forceinline__ float sigmoidf_(float z) {
    return 1.0f / (1.0f + expf(-z));
}

__device__ __forceinline__ unsigned short f2bf(float f) {
    union { float f; uint32_t u; } v; v.f = f;
    uint32_t u = v.u;
    return (unsigned short)((u + 0x7FFFu + ((u >> 16) & 1u)) >> 16);
}

// ---------------- prep: 64 blocks x 64 threads.
// Blocks 0..55: the 7 polyphase matrices as packed bf16 fragments:
//   frag (phase, ks, nt): lane l elem i = M[tap=ks>>1][c=(ks&1)*32+(l>>4)*8+i]
//                                          [f=nt*16+(l&15)]
// Blocks 56..63: b = fi-56; corr[b][{E,O}][f] = sum_c K[{1,0}][c][f]*(1-w_c)*x[b,0,c]
// Block 63 additionally zeroes the 256B zero-pad (OOB redirect target).
__global__ void lu_prep_kernel(const float* __restrict__ iw,
                               const float* __restrict__ ck,
                               const float* __restrict__ x,
                               unsigned short* __restrict__ bp,
                               float* __restrict__ corrf,
                               float* __restrict__ zp) {
    int fi = blockIdx.x;
    int l  = threadIdx.x;
    if (fi < 56) {
        int phase, ks, nt;
        if (fi < 24) { phase = 0; ks = fi >> 2; nt = fi & 3; }
        else         { phase = 1; ks = (fi - 24) >> 2; nt = (fi - 24) & 3; }
        int tap = ks >> 1;
        int n   = nt * 16 + (l & 15);
        int c0  = ((ks & 1) << 5) + ((l >> 4) << 3);
        u16x8 pk;
#pragma unroll
        for (int i = 0; i < 8; ++i) {
            int c = c0 + i;
            float w = sigmoidf_(iw[c]);
            float v;
            #define CK(k) ck[((k) * 64 + c) * 64 + n]
            if (phase == 0) {
                if (tap == 0)      v = CK(0) + w * CK(1);
                else if (tap == 1) v = (1.f - w) * CK(1) + CK(2) + w * CK(3);
                else               v = (1.f - w) * CK(3) + CK(4);
            } else {
                if (tap == 0)      v = w * CK(0);
                else if (tap == 1) v = (1.f - w) * CK(0) + CK(1) + w * CK(2);
                else if (tap == 2) v = (1.f - w) * CK(2) + CK(3) + w * CK(4);
                else               v = (1.f - w) * CK(4);
            }
            #undef CK
            pk[i] = f2bf(v);
        }
        *(u16x8*)(bp + (((size_t)fi * 64) + l) * 8) = pk;
    } else {
        int b = fi - 56;
        int f = l;
        float cE = 0.f, cO = 0.f;
#pragma unroll
        for (int c = 0; c < 64; ++c) {
            float w = sigmoidf_(iw[c]);
            float g = (1.f - w) * x[(size_t)b * T_ * 64 + c];
            cE += ck[(64 + c) * 64 + f] * g;   // K1
            cO += ck[c * 64 + f] * g;          // K0
        }
        corrf[b * 128 + f]      = cE;
        corrf[b * 128 + 64 + f] = cO;
        if (fi == 63) zp[l] = 0.f;             // 64 floats = 256 B zero pad
    }
}

// ---------------- main ----------------
__device__ __forceinline__ void gload16(const float* g, float* l) {
    __builtin_amdgcn_global_load_lds(
        (const __attribute__((address_space(1))) uint32_t*)g,
        (__attribute__((address_space(3))) uint32_t*)l, 16, 0, 0);
}

// Stage 4 frames f_rel = S..S+3 (S % 4 == 0, group contiguous mod RING).
// lane l: frame S+(l>>4), 16B-chunk slot s=l&15; source chunk = s ^ ((f_rel-1)&7)
// (XOR pre-swizzle on the GLOBAL side; reads apply the same XOR on the LDS
// side -> both-sides involution, linear DMA dest). OOB frames -> zero pad.
__device__ __forceinline__ void stage4(const float* __restrict__ xb,
                                       const float* __restrict__ zp,
                                       int p0, int S, int lane, float* xw) {
    int fr = S + (lane >> 4);           // f_rel
    int f  = p0 + fr - 1;               // frame index in batch
    int ch = (lane & 15) ^ ((fr - 1) & 7);
    const float* gp = ((unsigned)f < (unsigned)T_)
                    ? xb + ((size_t)f << 6) + (ch << 2)
                    : zp + (ch << 2);
    gload16(gp, xw + ((S % RING) << 6));
}

__device__ __forceinline__ bf16x8 pack8(f32x4 a, f32x4 b) {
    bf16x8 r;
    r[0] = (__bf16)a[0]; r[1] = (__bf16)a[1];
    r[2] = (__bf16)a[2]; r[3] = (__bf16)a[3];
    r[4] = (__bf16)b[0]; r[5] = (__bf16)b[1];
    r[6] = (__bf16)b[2]; r[7] = (__bf16)b[3];
    return r;
}

__global__ __launch_bounds__(256, 4) void lu_main_kernel(
        const float* __restrict__ x,
        const unsigned short* __restrict__ bp,
        const float* __restrict__ corrf,
        const float* __restrict__ bias,
        const float* __restrict__ zp,
        float* __restrict__ out) {
    __shared__ __align__(16) float xl[4][RING * 64];   // 40,960 B

    const int bid  = blockIdx.x;        // 0..2047
    const int b    = bid >> 8;
    const int q    = bid & 255;
    const int p0   = q << 6;            // first time-pair (64 per block)
    const int lane = threadIdx.x & 63;
    const int wv   = threadIdx.x >> 6;  // wave = filter tile

    float* xw = &xl[wv][0];
    const float* xb = x + (size_t)b * T_ * 64;

    // ---- weight A-fragments + bias FIRST (older than all DMAs/waits) ----
    bf16x8 We[6], Wo[8];
#pragma unroll
    for (int ks = 0; ks < 6; ++ks)
        We[ks] = __builtin_bit_cast(bf16x8,
            *(const u16x8*)(bp + (((size_t)(ks * 4 + wv)) * 64 + lane) * 8));
#pragma unroll
    for (int ks = 0; ks < 8; ++ks)
        Wo[ks] = __builtin_bit_cast(bf16x8,
            *(const u16x8*)(bp + (((size_t)(24 + ks * 4 + wv)) * 64 + lane) * 8));

    const int hi   = lane >> 4;
    const int hi2  = hi << 1;
    const int col  = lane & 15;         // time-pair within window
    const float4 bias4 = *(const float4*)(bias + (wv << 4) + (hi << 2));
    const char* xwb = (const char*)xw;

    // ---- prologue: stage f_rel 0..19 (frames p0-1 .. p0+18) ----
#pragma unroll
    for (int k = 0; k < 5; ++k) stage4(xb, zp, p0, k * 4, lane, xw);

#pragma unroll
    for (int w = 0; w < 4; ++w) {
        // ---- stage window w+1's 16 new frames (f_rel 16w+20 .. 16w+35) ----
        if (w < 3) {
#pragma unroll
            for (int k = 0; k < 4; ++k)
                stage4(xb, zp, p0, 20 + (w << 4) + (k << 2), lane, xw);
        }

        // ---- counted wait: this window's rows have landed; prefetch stays
        //      in flight (never vmcnt(0) in steady state) ----
        if (w == 0)      asm volatile("s_waitcnt vmcnt(4)" ::: "memory");
        else if (w < 3)  asm volatile("s_waitcnt vmcnt(6)" ::: "memory");
        else             asm volatile("s_waitcnt vmcnt(2)" ::: "memory");
        __builtin_amdgcn_sched_barrier(0);

        // ---- fragments from ring (XOR-swizzled reads) + 14 MFMA ----
        f32x4 accE = {0.f, 0.f, 0.f, 0.f};
        f32x4 accO = {0.f, 0.f, 0.f, 0.f};
#pragma unroll
        for (int tap = 0; tap < 4; ++tap) {
            int fr  = (w << 4) + col + tap;
            int row = fr - (fr >= RING ? RING : 0);
            int key = (fr - 1) & 7;
            int off0 = (row << 8) + ((hi2 ^ key) << 4);
            f32x4 qa = *(const f32x4*)(xwb + off0);
            f32x4 qb = *(const f32x4*)(xwb + (off0 ^ 16));
            f32x4 qc = *(const f32x4*)(xwb + off0 + 128);
            f32x4 qd = *(const f32x4*)(xwb + ((off0 + 128) ^ 16));
            bf16x8 x0 = pack8(qa, qb);          // channels 0-31 half
            bf16x8 x1 = pack8(qc, qd);          // channels 32-63 half
            if (tap < 3) {
                accE = __builtin_amdgcn_mfma_f32_16x16x32_bf16(We[tap * 2],     x0, accE, 0, 0, 0);
                accE = __builtin_amdgcn_mfma_f32_16x16x32_bf16(We[tap * 2 + 1], x1, accE, 0, 0, 0);
            }
            accO = __builtin_amdgcn_mfma_f32_16x16x32_bf16(Wo[tap * 2],     x0, accO, 0, 0, 0);
            accO = __builtin_amdgcn_mfma_f32_16x16x32_bf16(Wo[tap * 2 + 1], x1, accO, 0, 0, 0);
        }

        // ---- boundary correction (output frames 0,1 of each batch) ----
        if (((q | w) == 0) && col == 0) {
            const float4 cE4 = *(const float4*)(corrf + b * 128 + (wv << 4) + (hi << 2));
            const float4 cO4 = *(const float4*)(corrf + b * 128 + 64 + (wv << 4) + (hi << 2));
            accE[0] -= cE4.x; accE[1] -= cE4.y; accE[2] -= cE4.z; accE[3] -= cE4.w;
            accO[0] -= cO4.x; accO[1] -= cO4.y; accO[2] -= cO4.z; accO[3] -= cO4.w;
        }

        // ---- epilogue: bias + leaky_relu, one dwordx4 store per phase ----
        const int tl = p0 + (w << 4) + col;
        const size_t fbase = ((size_t)b * TWO_T + ((size_t)tl << 1)) * 64
                           + (wv << 4) + (hi << 2);
        float4 vE, vO;
        {
            float e0 = accE[0] + bias4.x, e1 = accE[1] + bias4.y,
                  e2 = accE[2] + bias4.z, e3 = accE[3] + bias4.w;
            vE.x = e0 >= 0.f ? e0 : 0.3f * e0;
            vE.y = e1 >= 0.f ? e1 : 0.3f * e1;
            vE.z = e2 >= 0.f ? e2 : 0.3f * e2;
            vE.w = e3 >= 0.f ? e3 : 0.3f * e3;
            float o0 = accO[0] + bias4.x, o1 = accO[1] + bias4.y,
                  o2 = accO[2] + bias4.z, o3 = accO[3] + bias4.w;
            vO.x = o0 >= 0.f ? o0 : 0.3f * o0;
            vO.y = o1 >= 0.f ? o1 : 0.3f * o1;
            vO.z = o2 >= 0.f ? o2 : 0.3f * o2;
            vO.w = o3 >= 0.f ? o3 : 0.3f * o3;
        }
        *(float4*)(out + fbase)      = vE;   // even frame 2*tl
        *(float4*)(out + fbase + 64) = vO;   // odd frame 2*tl+1
    }
}

extern "C" void kernel_launch(void* const* d_in, const int* in_sizes, int n_in,
                              void* d_out, int out_size, void* d_ws, size_t ws_size,
                              hipStream_t stream) {
    (void)in_sizes; (void)n_in; (void)out_size; (void)ws_size;
    const float* x    = (const float*)d_in[0];
    const float* iw   = (const float*)d_in[1];
    const float* ck   = (const float*)d_in[2];
    const float* bias = (const float*)d_in[3];
    float* out = (float*)d_out;
    unsigned short* bp = (unsigned short*)d_ws;            // 57,344 B
    float* corrf = (float*)((char*)d_ws + 57344);          // 4,096 B
    float* zp    = (float*)((char*)d_ws + 61440);          //   256 B zeros

    lu_prep_kernel<<<64, 64, 0, stream>>>(iw, ck, x, bp, corrf, zp);
    lu_main_kernel<<<2048, 256, 0, stream>>>(x, bp, corrf, bias, zp, out);
}

// Round 9
// 32.019 us; speedup vs baseline: 1.6685x; 1.0374x over previous
//
#include <hip/hip_runtime.h>
#include <hip/hip_bf16.h>
#include <cstdint>

// LearnableUpsamplingLayer: polyphase decomposition + bf16 MFMA.
// B=8, T=16384, C=64, F=64, filter=5, leaky 0.3.
// out[b,2t+p,f] = sum_tap M_p[tap][c,f] * x[t-1+tap, c]   (x outside [0,T) = 0)
// Even p=0: 3 taps; odd p=1: 4 taps. Frames 0,1 get a precomputed correction
// (the polyphase substitution leaks a (1-w)*x[0] term through blend[-1]).
//
// R9: block-shared staging (m97 pattern). One 68-frame f32 ring per BLOCK
// (17.4 KB) staged cooperatively via global_load_lds (5 DMAs per thread),
// ONE __syncthreads (its implied vmcnt(0) drain provides the DMA->ds_read
// ordering, as in the proven m97 structure), then 4 windows of
// ds_read + 14 MFMA + dwordx4 stores with no further syncs. Cross-block
// overlap (4 blocks/CU, 8 rounds) hides HBM latency instead of per-wave
// prefetch arithmetic. XOR involution swizzle on both the global source
// chunk and the LDS read offset keeps b128 reads spread over all 8 bank
// quads. Operand-swapped MFMA (W = A) so each thread owns 4 consecutive
// filters -> 2 global_store_dwordx4 per window.

#define T_ 16384
#define TWO_T 32768
#define NFR 68             // staged frames per block: p0-1 .. p0+66 (need 67)

typedef __bf16 bf16x8 __attribute__((ext_vector_type(8)));
typedef float  f32x4  __attribute__((ext_vector_type(4)));
typedef unsigned short u16x8 __attribute__((ext_vector_type(8)));

__device__ __forceinline__ float sigmoidf_(float z) {
    return 1.0f / (1.0f + expf(-z));
}

__device__ __forceinline__ unsigned short f2bf(float f) {
    union { float f; uint32_t u; } v; v.f = f;
    uint32_t u = v.u;
    return (unsigned short)((u + 0x7FFFu + ((u >> 16) & 1u)) >> 16);
}

// ---------------- prep: 64 blocks x 64 threads (unchanged, proven).
// Blocks 0..55: the 7 polyphase matrices as packed bf16 fragments:
//   frag (phase, ks, nt): lane l elem i = M[tap=ks>>1][c=(ks&1)*32+(l>>4)*8+i]
//                                          [f=nt*16+(l&15)]
// Blocks 56..63: b = fi-56; corr[b][{E,O}][f] = sum_c K[{1,0}][c][f]*(1-w_c)*x[b,0,c]
// Block 63 additionally zeroes the 256B zero-pad (OOB redirect target).
__global__ void lu_prep_kernel(const float* __restrict__ iw,
                               const float* __restrict__ ck,
                               const float* __restrict__ x,
                               unsigned short* __restrict__ bp,
                               float* __restrict__ corrf,
                               float* __restrict__ zp) {
    int fi = blockIdx.x;
    int l  = threadIdx.x;
    if (fi < 56) {
        int phase, ks, nt;
        if (fi < 24) { phase = 0; ks = fi >> 2; nt = fi & 3; }
        else         { phase = 1; ks = (fi - 24) >> 2; nt = (fi - 24) & 3; }
        int tap = ks >> 1;
        int n   = nt * 16 + (l & 15);
        int c0  = ((ks & 1) << 5) + ((l >> 4) << 3);
        u16x8 pk;
#pragma unroll
        for (int i = 0; i < 8; ++i) {
            int c = c0 + i;
            float w = sigmoidf_(iw[c]);
            float v;
            #define CK(k) ck[((k) * 64 + c) * 64 + n]
            if (phase == 0) {
                if (tap == 0)      v = CK(0) + w * CK(1);
                else if (tap == 1) v = (1.f - w) * CK(1) + CK(2) + w * CK(3);
                else               v = (1.f - w) * CK(3) + CK(4);
            } else {
                if (tap == 0)      v = w * CK(0);
                else if (tap == 1) v = (1.f - w) * CK(0) + CK(1) + w * CK(2);
                else if (tap == 2) v = (1.f - w) * CK(2) + CK(3) + w * CK(4);
                else               v = (1.f - w) * CK(4);
            }
            #undef CK
            pk[i] = f2bf(v);
        }
        *(u16x8*)(bp + (((size_t)fi * 64) + l) * 8) = pk;
    } else {
        int b = fi - 56;
        int f = l;
        float cE = 0.f, cO = 0.f;
#pragma unroll
        for (int c = 0; c < 64; ++c) {
            float w = sigmoidf_(iw[c]);
            float g = (1.f - w) * x[(size_t)b * T_ * 64 + c];
            cE += ck[(64 + c) * 64 + f] * g;   // K1
            cO += ck[c * 64 + f] * g;          // K0
        }
        corrf[b * 128 + f]      = cE;
        corrf[b * 128 + 64 + f] = cO;
        if (fi == 63) zp[l] = 0.f;             // 64 floats = 256 B zero pad
    }
}

// ---------------- main ----------------
__device__ __forceinline__ void gload16(const float* g, float* l) {
    __builtin_amdgcn_global_load_lds(
        (const __attribute__((address_space(1))) uint32_t*)g,
        (__attribute__((address_space(3))) uint32_t*)l, 16, 0, 0);
}

__device__ __forceinline__ bf16x8 pack8(f32x4 a, f32x4 b) {
    bf16x8 r;
    r[0] = (__bf16)a[0]; r[1] = (__bf16)a[1];
    r[2] = (__bf16)a[2]; r[3] = (__bf16)a[3];
    r[4] = (__bf16)b[0]; r[5] = (__bf16)b[1];
    r[6] = (__bf16)b[2]; r[7] = (__bf16)b[3];
    return r;
}

__global__ __launch_bounds__(256, 4) void lu_main_kernel(
        const float* __restrict__ x,
        const unsigned short* __restrict__ bp,
        const float* __restrict__ corrf,
        const float* __restrict__ bias,
        const float* __restrict__ zp,
        float* __restrict__ out) {
    __shared__ __align__(16) float xl[NFR * 64];   // 17,408 B, block-shared

    const int bid  = blockIdx.x;        // 0..2047
    const int b    = bid >> 8;
    const int q    = bid & 255;
    const int p0   = q << 6;            // first time-pair (64 per block)
    const int lane = threadIdx.x & 63;
    const int wv   = threadIdx.x >> 6;  // wave = filter tile

    const float* xb = x + (size_t)b * T_ * 64;

    // ---- weight A-fragments + bias (normal VGPR loads, oldest VMEM) ----
    bf16x8 We[6], Wo[8];
#pragma unroll
    for (int ks = 0; ks < 6; ++ks)
        We[ks] = __builtin_bit_cast(bf16x8,
            *(const u16x8*)(bp + (((size_t)(ks * 4 + wv)) * 64 + lane) * 8));
#pragma unroll
    for (int ks = 0; ks < 8; ++ks)
        Wo[ks] = __builtin_bit_cast(bf16x8,
            *(const u16x8*)(bp + (((size_t)(24 + ks * 4 + wv)) * 64 + lane) * 8));

    const int hi   = lane >> 4;
    const int hi2  = hi << 1;
    const int col  = lane & 15;         // time-pair within window
    const float4 bias4 = *(const float4*)(bias + (wv << 4) + (hi << 2));

    // ---- cooperative staging: frames p0-1 .. p0+66 -> LDS rows j=0..67.
    // Wave wv, group g stages rows j0..j0+3 (j0 = 16g + 4*wv, wave-uniform).
    // Lane: row j = j0 + (lane>>4), 16B-chunk slot s = lane&15; the global
    // source chunk is s ^ (j&7) (XOR involution; reads undo it). OOB -> zp.
#pragma unroll
    for (int g = 0; g < 5; ++g) {
        int j0 = g * 16 + (wv << 2);
        if (j0 < NFR) {
            int j  = j0 + (lane >> 4);
            int gf = p0 - 1 + j;
            int ch = (lane & 15) ^ (j & 7);
            const float* gp = ((unsigned)gf < (unsigned)T_)
                            ? xb + ((size_t)gf << 6) + (ch << 2)
                            : zp + (ch << 2);
            gload16(gp, xl + j0 * 64);
        }
    }

    // ---- the one barrier: implied s_waitcnt vmcnt(0) orders all DMAs
    //      (and the weight loads) before every ds_read below ----
    __syncthreads();

    const char* xwb = (const char*)xl;

#pragma unroll
    for (int w = 0; w < 4; ++w) {
        // ---- fragments from shared ring (XOR-swizzled reads) + 14 MFMA ----
        f32x4 accE = {0.f, 0.f, 0.f, 0.f};
        f32x4 accO = {0.f, 0.f, 0.f, 0.f};
#pragma unroll
        for (int tap = 0; tap < 4; ++tap) {
            int j    = (w << 4) + col + tap;        // row 0..66
            int key  = j & 7;
            int off0 = (j << 8) + ((hi2 ^ key) << 4);
            f32x4 qa = *(const f32x4*)(xwb + off0);
            f32x4 qb = *(const f32x4*)(xwb + (off0 ^ 16));
            f32x4 qc = *(const f32x4*)(xwb + off0 + 128);
            f32x4 qd = *(const f32x4*)(xwb + ((off0 + 128) ^ 16));
            bf16x8 x0 = pack8(qa, qb);              // channels 0-31 half
            bf16x8 x1 = pack8(qc, qd);              // channels 32-63 half
            if (tap < 3) {
                accE = __builtin_amdgcn_mfma_f32_16x16x32_bf16(We[tap * 2],     x0, accE, 0, 0, 0);
                accE = __builtin_amdgcn_mfma_f32_16x16x32_bf16(We[tap * 2 + 1], x1, accE, 0, 0, 0);
            }
            accO = __builtin_amdgcn_mfma_f32_16x16x32_bf16(Wo[tap * 2],     x0, accO, 0, 0, 0);
            accO = __builtin_amdgcn_mfma_f32_16x16x32_bf16(Wo[tap * 2 + 1], x1, accO, 0, 0, 0);
        }

        // ---- boundary correction (output frames 0,1 of each batch) ----
        if (((q | w) == 0) && col == 0) {
            const float4 cE4 = *(const float4*)(corrf + b * 128 + (wv << 4) + (hi << 2));
            const float4 cO4 = *(const float4*)(corrf + b * 128 + 64 + (wv << 4) + (hi << 2));
            accE[0] -= cE4.x; accE[1] -= cE4.y; accE[2] -= cE4.z; accE[3] -= cE4.w;
            accO[0] -= cO4.x; accO[1] -= cO4.y; accO[2] -= cO4.z; accO[3] -= cO4.w;
        }

        // ---- epilogue: bias + leaky_relu, one dwordx4 store per phase ----
        const int tl = p0 + (w << 4) + col;
        const size_t fbase = ((size_t)b * TWO_T + ((size_t)tl << 1)) * 64
                           + (wv << 4) + (hi << 2);
        float4 vE, vO;
        {
            float e0 = accE[0] + bias4.x, e1 = accE[1] + bias4.y,
                  e2 = accE[2] + bias4.z, e3 = accE[3] + bias4.w;
            vE.x = e0 >= 0.f ? e0 : 0.3f * e0;
            vE.y = e1 >= 0.f ? e1 : 0.3f * e1;
            vE.z = e2 >= 0.f ? e2 : 0.3f * e2;
            vE.w = e3 >= 0.f ? e3 : 0.3f * e3;
            float o0 = accO[0] + bias4.x, o1 = accO[1] + bias4.y,
                  o2 = accO[2] + bias4.z, o3 = accO[3] + bias4.w;
            vO.x = o0 >= 0.f ? o0 : 0.3f * o0;
            vO.y = o1 >= 0.f ? o1 : 0.3f * o1;
            vO.z = o2 >= 0.f ? o2 : 0.3f * o2;
            vO.w = o3 >= 0.f ? o3 : 0.3f * o3;
        }
        *(float4*)(out + fbase)      = vE;   // even frame 2*tl
        *(float4*)(out + fbase + 64) = vO;   // odd frame 2*tl+1
    }
}

extern "C" void kernel_launch(void* const* d_in, const int* in_sizes, int n_in,
                              void* d_out, int out_size, void* d_ws, size_t ws_size,
                              hipStream_t stream) {
    (void)in_sizes; (void)n_in; (void)out_size; (void)ws_size;
    const float* x    = (const float*)d_in[0];
    const float* iw   = (const float*)d_in[1];
    const float* ck   = (const float*)d_in[2];
    const float* bias = (const float*)d_in[3];
    float* out = (float*)d_out;
    unsigned short* bp = (unsigned short*)d_ws;            // 57,344 B
    float* corrf = (float*)((char*)d_ws + 57344);          // 4,096 B
    float* zp    = (float*)((char*)d_ws + 61440);          //   256 B zeros

    lu_prep_kernel<<<64, 64, 0, stream>>>(iw, ck, x, bp, corrf, zp);
    lu_main_kernel<<<2048, 256, 0, stream>>>(x, bp, corrf, bias, zp, out);
}